// Round 6
// baseline (282.511 us; speedup 1.0000x reference)
//
#include <hip/hip_runtime.h>

#define NN 50000
#define NE 800000
#define S 4                         // src bins per row (L2-resident gather slices)
#define BINW 12500                  // NN / S exactly
#define NN4 (NN * S)                // 200000 split-CSR buckets
#define NBLK2 ((NN4 + 255) / 256)   // 782 scan blocks
#define NBG ((NN + 63) / 64)        // 782 gemm1 blocks
#define NBH4 ((NE / 4 + 255) / 256) // 782 blocks: 4-edge threads (also covers NN4 pad-fill)
#define COLCAP (NE + 3 * NN4 + 8)   // padded col capacity + slack

// ---------------- hist: 4 edges/thread, 4 atomics in flight ----------------
__global__ __launch_bounds__(256) void hist_k(const int* __restrict__ src,
                                              const int* __restrict__ dst,
                                              int* __restrict__ cnt,
                                              int* __restrict__ rank) {
    int e = (blockIdx.x * 256 + threadIdx.x) * 4;
    if (e >= NE) return;
    int4 s4 = *(const int4*)(src + e);
    int4 d4 = *(const int4*)(dst + e);
    int4 r;
    r.x = atomicAdd(&cnt[d4.x * S + s4.x / BINW], 1);
    r.y = atomicAdd(&cnt[d4.y * S + s4.y / BINW], 1);
    r.z = atomicAdd(&cnt[d4.z * S + s4.z / BINW], 1);
    r.w = atomicAdd(&cnt[d4.w * S + s4.w / BINW], 1);
    *(int4*)(rank + e) = r;
}

// ---- scan over NN4 buckets with per-bucket pad-to-4: cnt -> rowsS ----
// phase 1: per-block sums of padded counts; dinv = rsqrt(raw deg + 1);
// block 0 also zeroes the sentinel rows (runs before any prop).
__global__ __launch_bounds__(256) void sum_blocks_k(const int* __restrict__ cnt,
                                                    int* __restrict__ bsum,
                                                    float* __restrict__ dinv,
                                                    float* __restrict__ y1s,
                                                    float* __restrict__ y2s,
                                                    float* __restrict__ z1s,
                                                    float* __restrict__ z2s) {
    __shared__ int s[256];
    int t = threadIdx.x;
    int i = blockIdx.x * 256 + t;
    if (blockIdx.x == 0) {
        if (t < 64) { y1s[t] = 0.f; y2s[t] = 0.f; }
        else if (t < 96) { z1s[t - 64] = 0.f; z2s[t - 64] = 0.f; }
    }
    int v = 0;
    if (i < NN4) {
        int c = cnt[i];
        v = (c + 3) & ~3;                 // bucket padded to multiple of 4
        if ((i & 3) == 0) {
            int deg = c + cnt[i + 1] + cnt[i + 2] + cnt[i + 3];
            dinv[i >> 2] = rsqrtf((float)(deg + 1));  // +1 self loop (raw deg)
        }
    }
    s[t] = v;
    __syncthreads();
    for (int off = 128; off > 0; off >>= 1) {
        if (t < off) s[t] += s[t + off];
        __syncthreads();
    }
    if (t == 0) bsum[blockIdx.x] = s[0];
}

// phase 2: per-block exclusive scan of padded counts; block offset derived by
// summing preceding bsum entries (3KB, L2-hit). Last thread writes grand total.
__global__ __launch_bounds__(256) void scan_final_k(const int* __restrict__ cnt,
                                                    const int* __restrict__ bsum,
                                                    int* __restrict__ rowsS) {
    __shared__ int sOff[256];
    __shared__ int s[256];
    int t = threadIdx.x;
    int accum = 0;
    for (int idx = t; idx < NBLK2; idx += 256)
        if (idx < blockIdx.x) accum += bsum[idx];
    sOff[t] = accum;
    __syncthreads();
    for (int off = 128; off > 0; off >>= 1) {
        if (t < off) sOff[t] += sOff[t + off];
        __syncthreads();
    }
    int boff = sOff[0];

    int i = blockIdx.x * 256 + t;
    int v = (i < NN4) ? ((cnt[i] + 3) & ~3) : 0;
    s[t] = v;
    __syncthreads();
    for (int off = 1; off < 256; off <<= 1) {
        int x = (t >= off) ? s[t - off] : 0;
        __syncthreads();
        s[t] += x;
        __syncthreads();
    }
    if (i < NN4) rowsS[i] = boff + s[t] - v;  // exclusive (padded space)
    if (blockIdx.x == NBLK2 - 1 && t == 255) rowsS[NN4] = boff + s[t];
}

// ---------------- merged: layer-1 GEMM || scatter + pad fill ----------------
// blocks [0, NBG): outA = A@WA (unscaled), outB = dinv .* (A@WB)  (pre-scaled
//                  for the weight-factored propagation)
// blocks [NBG, NBG+NBH4): 4-edge scatter into padded col + sentinel pad fill
__global__ __launch_bounds__(256) void gemm1_scatter_k(const float* __restrict__ A,
                                                       const float* __restrict__ WA,
                                                       const float* __restrict__ WB,
                                                       float* __restrict__ outA,
                                                       float* __restrict__ outB,
                                                       const int* __restrict__ src,
                                                       const int* __restrict__ dst,
                                                       const int* __restrict__ rank,
                                                       const int* __restrict__ rowsS,
                                                       const int* __restrict__ cnt,
                                                       int* __restrict__ col,
                                                       const float* __restrict__ dinv) {
    if (blockIdx.x >= NBG) {
        int idx = (blockIdx.x - NBG) * 256 + threadIdx.x;
        int e = idx * 4;
        if (e < NE) {
            int4 s4 = *(const int4*)(src + e);
            int4 d4 = *(const int4*)(dst + e);
            int4 r4 = *(const int4*)(rank + e);
            col[rowsS[d4.x * S + s4.x / BINW] + r4.x] = s4.x;
            col[rowsS[d4.y * S + s4.y / BINW] + r4.y] = s4.y;
            col[rowsS[d4.z * S + s4.z / BINW] + r4.z] = s4.z;
            col[rowsS[d4.w * S + s4.w / BINW] + r4.w] = s4.w;
        }
        if (idx < NN4) {                       // fill <=3 pad slots of bucket idx
            int end = rowsS[idx] + cnt[idx];
            int nxt = rowsS[idx + 1];
            for (int i = end; i < nxt; i++) col[i] = NN;   // sentinel: zero row
        }
        return;
    }

    __shared__ float As[64 * 36];    // 64 nodes x 32 k (+4 pad)
    __shared__ float W1s[32 * 68];   // 32 k x 64 j (+4 pad)
    __shared__ float W2s[32 * 68];
    const int t = threadIdx.x;
    const int tj = t & 15;
    const int tn = t >> 4;
    const int n0 = blockIdx.x * 64;
    float acc[4][8] = {};

    for (int kc = 0; kc < 128; kc += 32) {
        if (kc) __syncthreads();
        {
            int idx = t;
#pragma unroll
            for (int r = 0; r < 2; r++, idx += 256) {   // 512 float4 = 64x32 floats
                int nl = idx >> 3, q = idx & 7;
                int node = n0 + nl; node = node < NN ? node : NN - 1;
                float4 a = ((const float4*)A)[(size_t)node * 32 + (kc >> 2) + q];
                *(float4*)&As[nl * 36 + q * 4] = a;
            }
        }
        {
            int idx = t;
#pragma unroll
            for (int r = 0; r < 2; r++, idx += 256) {   // 512 float4 = 2 x 32x64
                int kl = idx >> 4, j4 = idx & 15;
                *(float4*)&W1s[kl * 68 + j4 * 4] = ((const float4*)WA)[(size_t)(kc + kl) * 16 + j4];
                *(float4*)&W2s[kl * 68 + j4 * 4] = ((const float4*)WB)[(size_t)(kc + kl) * 16 + j4];
            }
        }
        __syncthreads();

        const float* ap = &As[tn * 4 * 36];
        const float* w1p = &W1s[tj * 4];
        const float* w2p = &W2s[tj * 4];
#pragma unroll 2
        for (int k4 = 0; k4 < 8; k4++) {
            float4 a0 = *(const float4*)&ap[0 * 36 + k4 * 4];
            float4 a1 = *(const float4*)&ap[1 * 36 + k4 * 4];
            float4 a2 = *(const float4*)&ap[2 * 36 + k4 * 4];
            float4 a3 = *(const float4*)&ap[3 * 36 + k4 * 4];
#pragma unroll
            for (int kk = 0; kk < 4; kk++) {
                float4 w1 = *(const float4*)&w1p[(k4 * 4 + kk) * 68];
                float4 w2 = *(const float4*)&w2p[(k4 * 4 + kk) * 68];
                float av0 = kk == 0 ? a0.x : kk == 1 ? a0.y : kk == 2 ? a0.z : a0.w;
                float av1 = kk == 0 ? a1.x : kk == 1 ? a1.y : kk == 2 ? a1.z : a1.w;
                float av2 = kk == 0 ? a2.x : kk == 1 ? a2.y : kk == 2 ? a2.z : a2.w;
                float av3 = kk == 0 ? a3.x : kk == 1 ? a3.y : kk == 2 ? a3.z : a3.w;
#define FMA8(m, AV)                                                     \
                acc[m][0] += AV * w1.x; acc[m][1] += AV * w1.y;          \
                acc[m][2] += AV * w1.z; acc[m][3] += AV * w1.w;          \
                acc[m][4] += AV * w2.x; acc[m][5] += AV * w2.y;          \
                acc[m][6] += AV * w2.z; acc[m][7] += AV * w2.w;
                FMA8(0, av0)
                FMA8(1, av1)
                FMA8(2, av2)
                FMA8(3, av3)
#undef FMA8
            }
        }
    }

#pragma unroll
    for (int m = 0; m < 4; m++) {
        int node = n0 + tn * 4 + m;
        if (node < NN) {
            float dnm = dinv[node];
            *(float4*)&outA[(size_t)node * 64 + tj * 4] =
                make_float4(acc[m][0], acc[m][1], acc[m][2], acc[m][3]);
            *(float4*)&outB[(size_t)node * 64 + tj * 4] =
                make_float4(dnm * acc[m][4], dnm * acc[m][5],
                            dnm * acc[m][6], dnm * acc[m][7]);
        }
    }
}

// ---------------- propagation (weight-factored, bin-phased, tail-free) ----------------
// Input h' = dinv .* h (pre-scaled by producer). P(h)[d] = dinv[d]*(sum h'[s]
// + h'[d]). Four per-bin sub-loops: waves reconverge at bin boundaries, so
// co-resident blocks' gathers concentrate on one ~3.2MB source slice at a
// time (per-XCD-L2-resident). Buckets padded to x4 -> every sub-loop is
// tail-free; pad slots (col=NN) gather the zeroed sentinel row.
// ADDIN=true:  out = dinv .* (addin + dn*g)   (pre-scaled for the next prop)
// ADDIN=false: out = relu(bias + dn*g)        (final layer output, unscaled)
template<int LOG2C4, bool ADDIN>
__global__ __launch_bounds__(256) void prop_k(const float4* __restrict__ h4,
                                              const float4* __restrict__ addin4,
                                              const float* __restrict__ bias,
                                              float4* __restrict__ out4,
                                              const int* __restrict__ rowsS,
                                              const int* __restrict__ col,
                                              const float* __restrict__ dinv) {
    const int C4 = 1 << LOG2C4;
    unsigned tid = blockIdx.x * blockDim.x + threadIdx.x;
    unsigned node = tid >> LOG2C4;
    if (node >= NN) return;
    unsigned lane = tid & (C4 - 1);
    size_t rowoff = ((size_t)node << LOG2C4) + lane;
    float dn = dinv[node];
    float4 g = h4[rowoff];                        // self term h'[node]
    int4 rp = *(const int4*)(rowsS + (node << 2));
    int rb0 = rp.x, rb1 = rp.y, rb2 = rp.z, rb3 = rp.w;
    int rb4 = rowsS[(node << 2) + 4];
#pragma unroll
    for (int p = 0; p < 4; p++) {
        int i  = (p == 0) ? rb0 : (p == 1) ? rb1 : (p == 2) ? rb2 : rb3;
        int re = (p == 0) ? rb1 : (p == 1) ? rb2 : (p == 2) ? rb3 : rb4;
        for (; i < re; i += 4) {
            int4 cc = *(const int4*)(col + i);
            float4 v0 = h4[((size_t)cc.x << LOG2C4) + lane];
            float4 v1 = h4[((size_t)cc.y << LOG2C4) + lane];
            float4 v2 = h4[((size_t)cc.z << LOG2C4) + lane];
            float4 v3 = h4[((size_t)cc.w << LOG2C4) + lane];
            g.x += v0.x + v1.x + v2.x + v3.x;
            g.y += v0.y + v1.y + v2.y + v3.y;
            g.z += v0.z + v1.z + v2.z + v3.z;
            g.w += v0.w + v1.w + v2.w + v3.w;
        }
    }
    float4 acc;
    if (ADDIN) {
        float4 a = addin4[rowoff];
        acc.x = dn * (a.x + dn * g.x);
        acc.y = dn * (a.y + dn * g.y);
        acc.z = dn * (a.z + dn * g.z);
        acc.w = dn * (a.w + dn * g.w);
    } else {
        float4 b = ((const float4*)bias)[lane];
        acc.x = fmaxf(b.x + dn * g.x, 0.0f);
        acc.y = fmaxf(b.y + dn * g.y, 0.0f);
        acc.z = fmaxf(b.z + dn * g.z, 0.0f);
        acc.w = fmaxf(b.w + dn * g.w, 0.0f);
    }
    out4[rowoff] = acc;
}

// ---------------- layer-2 GEMM: z1 = A@WA, z2' = dinv .* (A@WB) ----------------
template<int K, int JW>
__global__ __launch_bounds__(256) void gemm_k(const float* __restrict__ A,
                                              const float* __restrict__ WA,
                                              const float* __restrict__ WB,
                                              float* __restrict__ outA,
                                              float* __restrict__ outB, int n,
                                              const float* __restrict__ dinv) {
    __shared__ float As[64 * 68];
    __shared__ float Ws[64 * 68];
    const int t = threadIdx.x;
    const int tj = t & 15;
    const int tn = t >> 4;
    const int n0 = blockIdx.x * 64;
    float acc[4][4] = {};

    for (int kc = 0; kc < K; kc += 64) {
        if (kc) __syncthreads();
        {
            int idx = t;
#pragma unroll
            for (int r = 0; r < 4; r++, idx += 256) {
                int nl = idx >> 4, q = idx & 15;
                int node = n0 + nl; node = node < n ? node : n - 1;
                float4 a = ((const float4*)A)[(size_t)node * (K / 4) + (kc >> 2) + q];
                *(float4*)&As[nl * 68 + q * 4] = a;
            }
        }
        {
            int idx = t;
#pragma unroll
            for (int r = 0; r < 4; r++, idx += 256) {
                int kl = idx >> 4, j4 = idx & 15;
                const float* W = (j4 < 8) ? WA : WB;
                float4 w = ((const float4*)W)[(size_t)(kc + kl) * 8 + (j4 & 7)];
                *(float4*)&Ws[kl * 68 + j4 * 4] = w;
            }
        }
        __syncthreads();

        const float* ap = &As[tn * 4 * 68];
        const float* wp = &Ws[tj * 4];
#pragma unroll 4
        for (int k4 = 0; k4 < 16; k4++) {
            float4 a0 = *(const float4*)&ap[0 * 68 + k4 * 4];
            float4 a1 = *(const float4*)&ap[1 * 68 + k4 * 4];
            float4 a2 = *(const float4*)&ap[2 * 68 + k4 * 4];
            float4 a3 = *(const float4*)&ap[3 * 68 + k4 * 4];
            float4 w0 = *(const float4*)&wp[(k4 * 4 + 0) * 68];
            float4 w1 = *(const float4*)&wp[(k4 * 4 + 1) * 68];
            float4 w2 = *(const float4*)&wp[(k4 * 4 + 2) * 68];
            float4 w3 = *(const float4*)&wp[(k4 * 4 + 3) * 68];
#define FMA_ROW(m, AV)                                                   \
            acc[m][0] += AV.x * w0.x + AV.y * w1.x + AV.z * w2.x + AV.w * w3.x; \
            acc[m][1] += AV.x * w0.y + AV.y * w1.y + AV.z * w2.y + AV.w * w3.y; \
            acc[m][2] += AV.x * w0.z + AV.y * w1.z + AV.z * w2.z + AV.w * w3.z; \
            acc[m][3] += AV.x * w0.w + AV.y * w1.w + AV.z * w2.w + AV.w * w3.w;
            FMA_ROW(0, a0)
            FMA_ROW(1, a1)
            FMA_ROW(2, a2)
            FMA_ROW(3, a3)
#undef FMA_ROW
        }
    }

    int mat = tj >> 3;
    float* ob = (mat ? outB : outA) + (tj & 7) * 4;
#pragma unroll
    for (int m = 0; m < 4; m++) {
        int node = n0 + tn * 4 + m;
        if (node < n) {
            float sc = mat ? dinv[node] : 1.0f;
            *(float4*)&ob[(size_t)node * JW] =
                make_float4(sc * acc[m][0], sc * acc[m][1],
                            sc * acc[m][2], sc * acc[m][3]);
        }
    }
}

// ---------------- fused: final prop (C=32) + heads, 8 threads/node ----------------
__global__ __launch_bounds__(256) void prop_heads_k(const float4* __restrict__ h4,
                                                    const float* __restrict__ b2,
                                                    const int* __restrict__ rowsS,
                                                    const int* __restrict__ col,
                                                    const float* __restrict__ dinv,
                                                    const float* __restrict__ Wp1, const float* __restrict__ bp1,
                                                    const float* __restrict__ Wp2, const float* __restrict__ bp2,
                                                    const float* __restrict__ Wc1, const float* __restrict__ bc1,
                                                    const float* __restrict__ Wc2, const float* __restrict__ bc2,
                                                    float* __restrict__ coord, float* __restrict__ z) {
    __shared__ float sWp1[32 * 32], sWp2[32 * 32], sWc1[32 * 16], sWc2[32];
    __shared__ float sbp1[32], sbp2[32], sbc1[16], sbc2[2];
    __shared__ float sh[32 * 36], st[32 * 36], stc[32 * 18];
    const int t = threadIdx.x;
    for (int i = t; i < 1024; i += 256) { sWp1[i] = Wp1[i]; sWp2[i] = Wp2[i]; }
    for (int i = t; i < 512; i += 256) sWc1[i] = Wc1[i];
    if (t < 32) { sWc2[t] = Wc2[t]; sbp1[t] = bp1[t]; sbp2[t] = bp2[t]; }
    if (t < 16) sbc1[t] = bc1[t];
    if (t < 2) sbc2[t] = bc2[t];

    const int n0 = blockIdx.x * 32;
    const int nl = t >> 3;
    const int jq = t & 7;
    const int node = n0 + nl;

    // ---- propagation for this node's 4-float fragment (bin-phased) ----
    float4 acc = make_float4(0.f, 0.f, 0.f, 0.f);
    if (node < NN) {
        size_t rowoff = ((size_t)node << 3) + jq;
        float dn = dinv[node];
        float4 g = h4[rowoff];                    // self term
        int4 rp = *(const int4*)(rowsS + (node << 2));
        int rb0 = rp.x, rb1 = rp.y, rb2 = rp.z, rb3 = rp.w;
        int rb4 = rowsS[(node << 2) + 4];
#pragma unroll
        for (int p = 0; p < 4; p++) {
            int i  = (p == 0) ? rb0 : (p == 1) ? rb1 : (p == 2) ? rb2 : rb3;
            int re = (p == 0) ? rb1 : (p == 1) ? rb2 : (p == 2) ? rb3 : rb4;
            for (; i < re; i += 4) {
                int4 cc = *(const int4*)(col + i);
                float4 v0 = h4[((size_t)cc.x << 3) + jq];
                float4 v1 = h4[((size_t)cc.y << 3) + jq];
                float4 v2 = h4[((size_t)cc.z << 3) + jq];
                float4 v3 = h4[((size_t)cc.w << 3) + jq];
                g.x += v0.x + v1.x + v2.x + v3.x;
                g.y += v0.y + v1.y + v2.y + v3.y;
                g.z += v0.z + v1.z + v2.z + v3.z;
                g.w += v0.w + v1.w + v2.w + v3.w;
            }
        }
        float4 b = ((const float4*)b2)[jq];
        acc.x = fmaxf(b.x + dn * g.x, 0.0f);
        acc.y = fmaxf(b.y + dn * g.y, 0.0f);
        acc.z = fmaxf(b.z + dn * g.z, 0.0f);
        acc.w = fmaxf(b.w + dn * g.w, 0.0f);
    }
    *(float4*)&sh[nl * 36 + jq * 4] = acc;
    __syncthreads();

    // ---- heads ----
    float4 a = *(const float4*)&sbp1[jq * 4];
#pragma unroll
    for (int k = 0; k < 32; k++) {
        float hv = sh[nl * 36 + k];
        float4 w = *(const float4*)&sWp1[k * 32 + jq * 4];
        a.x += hv * w.x; a.y += hv * w.y; a.z += hv * w.z; a.w += hv * w.w;
    }
    a.x = fmaxf(a.x, 0.f); a.y = fmaxf(a.y, 0.f);
    a.z = fmaxf(a.z, 0.f); a.w = fmaxf(a.w, 0.f);
    *(float4*)&st[nl * 36 + jq * 4] = a;

    float2 cc2 = *(const float2*)&sbc1[jq * 2];
#pragma unroll
    for (int k = 0; k < 32; k++) {
        float hv = sh[nl * 36 + k];
        float2 w = *(const float2*)&sWc1[k * 16 + jq * 2];
        cc2.x += hv * w.x; cc2.y += hv * w.y;
    }
    cc2.x = fmaxf(cc2.x, 0.f); cc2.y = fmaxf(cc2.y, 0.f);
    *(float2*)&stc[nl * 18 + jq * 2] = cc2;
    __syncthreads();

    float4 zz = *(const float4*)&sbp2[jq * 4];
#pragma unroll
    for (int k = 0; k < 32; k++) {
        float tv = st[nl * 36 + k];
        float4 w = *(const float4*)&sWp2[k * 32 + jq * 4];
        zz.x += tv * w.x; zz.y += tv * w.y; zz.z += tv * w.z; zz.w += tv * w.w;
    }
    if (node < NN) *(float4*)&z[(size_t)node * 32 + jq * 4] = zz;

    if (jq < 2) {
        float s = sbc2[jq];
#pragma unroll
        for (int k = 0; k < 16; k++) s += stc[nl * 18 + k] * sWc2[k * 2 + jq];
        if (node < NN) coord[(size_t)node * 2 + jq] = s;
    }
}

extern "C" void kernel_launch(void* const* d_in, const int* in_sizes, int n_in,
                              void* d_out, int out_size, void* d_ws, size_t ws_size,
                              hipStream_t stream) {
    const float* x    = (const float*)d_in[0];
    const int*   ei   = (const int*)d_in[1];
    const int*   src  = ei;
    const int*   dst  = ei + NE;
    const float* W1_1 = (const float*)d_in[2];
    const float* W1_2 = (const float*)d_in[3];
    const float* b1   = (const float*)d_in[4];
    const float* W2_1 = (const float*)d_in[5];
    const float* W2_2 = (const float*)d_in[6];
    const float* b2   = (const float*)d_in[7];
    const float* Wp1  = (const float*)d_in[8];
    const float* bp1  = (const float*)d_in[9];
    const float* Wp2  = (const float*)d_in[10];
    const float* bp2  = (const float*)d_in[11];
    const float* Wc1  = (const float*)d_in[12];
    const float* bc1  = (const float*)d_in[13];
    const float* Wc2  = (const float*)d_in[14];
    const float* bc2  = (const float*)d_in[15];

    // workspace layout (words), all segment offsets %4==0 -> 16B alignment:
    // dinv 50004 | cnt 200000 | rowsS 200004 | bsum 1024 | rank 800000 |
    // col COLCAP(1400008) | bufY (NN+1)*128 | bufZ (NN+1)*64   (~49 MB)
    float* ws    = (float*)d_ws;
    float* dinv  = ws;                              // NN (padded to 50004)
    int*   cnt   = (int*)(ws + 50004);              // NN4
    int*   rowsS = cnt + NN4;                       // NN4+4
    int*   bsum  = rowsS + NN4 + 4;                 // 1024
    int*   rank  = bsum + 1024;                     // NE
    int*   col   = rank + NE;                       // COLCAP
    float* bufY  = (float*)(col + COLCAP);          // (NN+1)*128
    float* bufZ  = bufY + (size_t)(NN + 1) * 128;   // (NN+1)*64

    float* y1 = bufY;                           // (NN+1)*64  (reused as u')
    float* y2 = bufY + (size_t)(NN + 1) * 64;   // (NN+1)*64  (= y2', reused as h1)
    float* u  = y1;                             // u' = dinv.*u
    float* h1 = y2;
    float* z1 = bufZ;                           // (NN+1)*32  (reused as u2')
    float* z2 = bufZ + (size_t)(NN + 1) * 32;   // (NN+1)*32  (= z2')
    float* u2 = z1;                             // u2' = dinv.*u2

    float* coord = (float*)d_out;                   // NN*2
    float* z     = (float*)d_out + 2 * NN;          // NN*32

    // 1) zero bucket counters (memset node in the graph, no kernel launch)
    hipMemsetAsync(cnt, 0, NN4 * sizeof(int), stream);
    // 2) hist: 4 edges/thread
    hist_k<<<NBH4, 256, 0, stream>>>(src, dst, cnt, rank);
    // 3) scan chain (padded buckets) + dinv + sentinel-row zeroing
    sum_blocks_k<<<NBLK2, 256, 0, stream>>>(cnt, bsum, dinv,
                                            y1 + (size_t)NN * 64, y2 + (size_t)NN * 64,
                                            z1 + (size_t)NN * 32, z2 + (size_t)NN * 32);
    scan_final_k<<<NBLK2, 256, 0, stream>>>(cnt, bsum, rowsS);
    // 4) gemm1 (y1 = xW1 unscaled, y2' = dinv.*xW2) || scatter+padfill
    gemm1_scatter_k<<<NBG + NBH4, 256, 0, stream>>>(x, W1_1, W1_2, y1, y2,
                                                    src, dst, rank, rowsS, cnt, col, dinv);

    // 5) u' = dinv.*(y1 + dn*(self+sum))   (C=64)
    prop_k<4, true><<<(NN * 16 + 255) / 256, 256, 0, stream>>>(
        (const float4*)y2, (const float4*)y1, nullptr, (float4*)u, rowsS, col, dinv);
    // 6) h1 = relu(b1 + dn*(self+sum))     (C=64, unscaled for gemm2)
    prop_k<4, false><<<(NN * 16 + 255) / 256, 256, 0, stream>>>(
        (const float4*)u, nullptr, b1, (float4*)h1, rowsS, col, dinv);
    // 7) z1 = h1@W2_1, z2' = dinv.*(h1@W2_2)  (K=64)
    gemm_k<64, 32><<<(NN + 63) / 64, 256, 0, stream>>>(h1, W2_1, W2_2, z1, z2, NN, dinv);
    // 8) u2' = dinv.*(z1 + dn*(self+sum))  (C=32)
    prop_k<3, true><<<(NN * 8 + 255) / 256, 256, 0, stream>>>(
        (const float4*)z2, (const float4*)z1, nullptr, (float4*)u2, rowsS, col, dinv);
    // 9) h2 = relu(b2 + dn*(self+sum)) fused with heads (h2 never hits HBM)
    prop_heads_k<<<(NN + 31) / 32, 256, 0, stream>>>(
        (const float4*)u2, b2, rowsS, col, dinv,
        Wp1, bp1, Wp2, bp2, Wc1, bc1, Wc2, bc2, coord, z);
}

// Round 7
// 256.955 us; speedup vs baseline: 1.0995x; 1.0995x over previous
//
#include <hip/hip_runtime.h>
#include <hip/hip_fp16.h>

#define NN 50000
#define NE 800000
#define S 4                         // src bins per row
#define BINW 12500                  // NN / S exactly
#define NN4 (NN * S)                // 200000 split-CSR buckets
#define NBLK2 ((NN4 + 255) / 256)   // 782 scan blocks
#define NBG ((NN + 63) / 64)        // 782 gemm1 blocks
#define NBH4 ((NE / 4 + 255) / 256) // 782 blocks: 4-edge threads (also covers NN4 pad-fill)
#define COLCAP (NE + 3 * NN4 + 8)   // padded col capacity + prefetch slack

// ---- fp16 helpers: 4 halfs per lane, single 8B load/store, fp32 math ----
__device__ __forceinline__ float4 ldh4(const __half2* p) {
    float2 raw = *(const float2*)p;             // one 8B load (2x __half2)
    __half2 a = *(__half2*)&raw.x;
    __half2 b = *(__half2*)&raw.y;
    float2 fa = __half22float2(a);
    float2 fb = __half22float2(b);
    return make_float4(fa.x, fa.y, fb.x, fb.y);
}
__device__ __forceinline__ void sth4(__half2* p, float4 v) {
    __half2 a = __floats2half2_rn(v.x, v.y);
    __half2 b = __floats2half2_rn(v.z, v.w);
    float2 raw;
    raw.x = *(float*)&a; raw.y = *(float*)&b;
    *(float2*)p = raw;                          // one 8B store
}

// ---------------- hist: 4 edges/thread, 4 atomics in flight ----------------
__global__ __launch_bounds__(256) void hist_k(const int* __restrict__ src,
                                              const int* __restrict__ dst,
                                              int* __restrict__ cnt,
                                              int* __restrict__ rank) {
    int e = (blockIdx.x * 256 + threadIdx.x) * 4;
    if (e >= NE) return;
    int4 s4 = *(const int4*)(src + e);
    int4 d4 = *(const int4*)(dst + e);
    int4 r;
    r.x = atomicAdd(&cnt[d4.x * S + s4.x / BINW], 1);
    r.y = atomicAdd(&cnt[d4.y * S + s4.y / BINW], 1);
    r.z = atomicAdd(&cnt[d4.z * S + s4.z / BINW], 1);
    r.w = atomicAdd(&cnt[d4.w * S + s4.w / BINW], 1);
    *(int4*)(rank + e) = r;
}

// ---- scan over NN4 buckets with per-bucket pad-to-4: cnt -> rowsS ----
// phase 1: per-block sums of padded counts; dinv = rsqrt(raw deg + 1);
// block 0 zeroes the fp16 sentinel rows (row NN of each gather table).
__global__ __launch_bounds__(256) void sum_blocks_k(const int* __restrict__ cnt,
                                                    int* __restrict__ bsum,
                                                    float* __restrict__ dinv,
                                                    unsigned* __restrict__ y2h_s,
                                                    unsigned* __restrict__ uh_s,
                                                    unsigned* __restrict__ z2h_s,
                                                    unsigned* __restrict__ u2h_s) {
    __shared__ int s[256];
    int t = threadIdx.x;
    int i = blockIdx.x * 256 + t;
    if (blockIdx.x == 0) {
        if (t < 32) { y2h_s[t] = 0u; uh_s[t] = 0u; }        // 64 halfs each
        else if (t < 48) { z2h_s[t - 32] = 0u; u2h_s[t - 32] = 0u; }  // 32 halfs
    }
    int v = 0;
    if (i < NN4) {
        int c = cnt[i];
        v = (c + 3) & ~3;                 // bucket padded to multiple of 4
        if ((i & 3) == 0) {
            int deg = c + cnt[i + 1] + cnt[i + 2] + cnt[i + 3];
            dinv[i >> 2] = rsqrtf((float)(deg + 1));  // +1 self loop (raw deg)
        }
    }
    s[t] = v;
    __syncthreads();
    for (int off = 128; off > 0; off >>= 1) {
        if (t < off) s[t] += s[t + off];
        __syncthreads();
    }
    if (t == 0) bsum[blockIdx.x] = s[0];
}

// phase 2: per-block exclusive scan of padded counts; block offset derived by
// summing preceding bsum entries (3KB, L2-hit). Last thread writes grand total.
__global__ __launch_bounds__(256) void scan_final_k(const int* __restrict__ cnt,
                                                    const int* __restrict__ bsum,
                                                    int* __restrict__ rowsS) {
    __shared__ int sOff[256];
    __shared__ int s[256];
    int t = threadIdx.x;
    int accum = 0;
    for (int idx = t; idx < NBLK2; idx += 256)
        if (idx < blockIdx.x) accum += bsum[idx];
    sOff[t] = accum;
    __syncthreads();
    for (int off = 128; off > 0; off >>= 1) {
        if (t < off) sOff[t] += sOff[t + off];
        __syncthreads();
    }
    int boff = sOff[0];

    int i = blockIdx.x * 256 + t;
    int v = (i < NN4) ? ((cnt[i] + 3) & ~3) : 0;
    s[t] = v;
    __syncthreads();
    for (int off = 1; off < 256; off <<= 1) {
        int x = (t >= off) ? s[t - off] : 0;
        __syncthreads();
        s[t] += x;
        __syncthreads();
    }
    if (i < NN4) rowsS[i] = boff + s[t] - v;  // exclusive (padded space)
    if (blockIdx.x == NBLK2 - 1 && t == 255) rowsS[NN4] = boff + s[t];
}

// ---------------- merged: layer-1 GEMM || scatter + pad fill ----------------
// blocks [0, NBG): outA = A@WA (fp32, addin path); outBh = fp16(dinv.*(A@WB))
//                  (the gather table for prop5 -- half payload)
// blocks [NBG, NBG+NBH4): 4-edge scatter into padded col + sentinel pad fill
__global__ __launch_bounds__(256) void gemm1_scatter_k(const float* __restrict__ A,
                                                       const float* __restrict__ WA,
                                                       const float* __restrict__ WB,
                                                       float* __restrict__ outA,
                                                       __half2* __restrict__ outBh,
                                                       const int* __restrict__ src,
                                                       const int* __restrict__ dst,
                                                       const int* __restrict__ rank,
                                                       const int* __restrict__ rowsS,
                                                       const int* __restrict__ cnt,
                                                       int* __restrict__ col,
                                                       const float* __restrict__ dinv) {
    if (blockIdx.x >= NBG) {
        int idx = (blockIdx.x - NBG) * 256 + threadIdx.x;
        int e = idx * 4;
        if (e < NE) {
            int4 s4 = *(const int4*)(src + e);
            int4 d4 = *(const int4*)(dst + e);
            int4 r4 = *(const int4*)(rank + e);
            col[rowsS[d4.x * S + s4.x / BINW] + r4.x] = s4.x;
            col[rowsS[d4.y * S + s4.y / BINW] + r4.y] = s4.y;
            col[rowsS[d4.z * S + s4.z / BINW] + r4.z] = s4.z;
            col[rowsS[d4.w * S + s4.w / BINW] + r4.w] = s4.w;
        }
        if (idx < NN4) {                       // fill <=3 pad slots of bucket idx
            int end = rowsS[idx] + cnt[idx];
            int nxt = rowsS[idx + 1];
            for (int i = end; i < nxt; i++) col[i] = NN;   // sentinel: zero row
        }
        return;
    }

    __shared__ float As[64 * 36];    // 64 nodes x 32 k (+4 pad)
    __shared__ float W1s[32 * 68];   // 32 k x 64 j (+4 pad)
    __shared__ float W2s[32 * 68];
    const int t = threadIdx.x;
    const int tj = t & 15;
    const int tn = t >> 4;
    const int n0 = blockIdx.x * 64;
    float acc[4][8] = {};

    for (int kc = 0; kc < 128; kc += 32) {
        if (kc) __syncthreads();
        {
            int idx = t;
#pragma unroll
            for (int r = 0; r < 2; r++, idx += 256) {   // 512 float4 = 64x32 floats
                int nl = idx >> 3, q = idx & 7;
                int node = n0 + nl; node = node < NN ? node : NN - 1;
                float4 a = ((const float4*)A)[(size_t)node * 32 + (kc >> 2) + q];
                *(float4*)&As[nl * 36 + q * 4] = a;
            }
        }
        {
            int idx = t;
#pragma unroll
            for (int r = 0; r < 2; r++, idx += 256) {   // 512 float4 = 2 x 32x64
                int kl = idx >> 4, j4 = idx & 15;
                *(float4*)&W1s[kl * 68 + j4 * 4] = ((const float4*)WA)[(size_t)(kc + kl) * 16 + j4];
                *(float4*)&W2s[kl * 68 + j4 * 4] = ((const float4*)WB)[(size_t)(kc + kl) * 16 + j4];
            }
        }
        __syncthreads();

        const float* ap = &As[tn * 4 * 36];
        const float* w1p = &W1s[tj * 4];
        const float* w2p = &W2s[tj * 4];
#pragma unroll 2
        for (int k4 = 0; k4 < 8; k4++) {
            float4 a0 = *(const float4*)&ap[0 * 36 + k4 * 4];
            float4 a1 = *(const float4*)&ap[1 * 36 + k4 * 4];
            float4 a2 = *(const float4*)&ap[2 * 36 + k4 * 4];
            float4 a3 = *(const float4*)&ap[3 * 36 + k4 * 4];
#pragma unroll
            for (int kk = 0; kk < 4; kk++) {
                float4 w1 = *(const float4*)&w1p[(k4 * 4 + kk) * 68];
                float4 w2 = *(const float4*)&w2p[(k4 * 4 + kk) * 68];
                float av0 = kk == 0 ? a0.x : kk == 1 ? a0.y : kk == 2 ? a0.z : a0.w;
                float av1 = kk == 0 ? a1.x : kk == 1 ? a1.y : kk == 2 ? a1.z : a1.w;
                float av2 = kk == 0 ? a2.x : kk == 1 ? a2.y : kk == 2 ? a2.z : a2.w;
                float av3 = kk == 0 ? a3.x : kk == 1 ? a3.y : kk == 2 ? a3.z : a3.w;
#define FMA8(m, AV)                                                     \
                acc[m][0] += AV * w1.x; acc[m][1] += AV * w1.y;          \
                acc[m][2] += AV * w1.z; acc[m][3] += AV * w1.w;          \
                acc[m][4] += AV * w2.x; acc[m][5] += AV * w2.y;          \
                acc[m][6] += AV * w2.z; acc[m][7] += AV * w2.w;
                FMA8(0, av0)
                FMA8(1, av1)
                FMA8(2, av2)
                FMA8(3, av3)
#undef FMA8
            }
        }
    }

#pragma unroll
    for (int m = 0; m < 4; m++) {
        int node = n0 + tn * 4 + m;
        if (node < NN) {
            float dnm = dinv[node];
            *(float4*)&outA[(size_t)node * 64 + tj * 4] =
                make_float4(acc[m][0], acc[m][1], acc[m][2], acc[m][3]);
            sth4(outBh + (size_t)node * 32 + tj * 2,
                 make_float4(dnm * acc[m][4], dnm * acc[m][5],
                             dnm * acc[m][6], dnm * acc[m][7]));
        }
    }
}

// ---------------- propagation (weight-factored, fp16 gather, tail-free) ----------------
// Gather table h' = fp16(dinv .* h): 128B rows at C=64 (2 cache lines vs 4).
// P(h)[d] = dinv[d]*(sum h'[s] + h'[d]). Accumulation in fp32.
// ADDIN=true:  out = dinv .* (addin_f32 + dn*g)  -> fp16 (next gather table)
// ADDIN=false: out = relu(bias + dn*g)           -> fp32 (dense consumer)
template<int LOG2C4, bool ADDIN, bool OUTH>
__global__ __launch_bounds__(256) void prop_k(const __half2* __restrict__ hsrc,
                                              const float4* __restrict__ addin4,
                                              const float* __restrict__ bias,
                                              float4* __restrict__ outf,
                                              __half2* __restrict__ outh,
                                              const int* __restrict__ rowsS,
                                              const int* __restrict__ col,
                                              const float* __restrict__ dinv) {
    const int C4 = 1 << LOG2C4;           // lanes per node
    const int R2 = 2 * C4;                // __half2 per row
    unsigned tid = blockIdx.x * blockDim.x + threadIdx.x;
    unsigned node = tid >> LOG2C4;
    if (node >= NN) return;
    unsigned lane = tid & (C4 - 1);
    size_t lane2 = (size_t)lane * 2;
    float dn = dinv[node];
    float4 g = ldh4(hsrc + (size_t)node * R2 + lane2);   // self term
    int rs = rowsS[node << 2];
    int re = rowsS[(node << 2) + 4];
    int4 c = *(const int4*)(col + rs);                   // slack-protected
    for (int i = rs; i < re; i += 4) {
        int4 cc = c;
        c = *(const int4*)(col + i + 4);                 // prefetch next
        float4 v0 = ldh4(hsrc + (size_t)cc.x * R2 + lane2);
        float4 v1 = ldh4(hsrc + (size_t)cc.y * R2 + lane2);
        float4 v2 = ldh4(hsrc + (size_t)cc.z * R2 + lane2);
        float4 v3 = ldh4(hsrc + (size_t)cc.w * R2 + lane2);
        g.x += v0.x + v1.x + v2.x + v3.x;
        g.y += v0.y + v1.y + v2.y + v3.y;
        g.z += v0.z + v1.z + v2.z + v3.z;
        g.w += v0.w + v1.w + v2.w + v3.w;
    }
    float4 acc;
    if (ADDIN) {
        float4 a = addin4[((size_t)node << LOG2C4) + lane];
        acc.x = dn * (a.x + dn * g.x);
        acc.y = dn * (a.y + dn * g.y);
        acc.z = dn * (a.z + dn * g.z);
        acc.w = dn * (a.w + dn * g.w);
    } else {
        float4 b = ((const float4*)bias)[lane];
        acc.x = fmaxf(b.x + dn * g.x, 0.0f);
        acc.y = fmaxf(b.y + dn * g.y, 0.0f);
        acc.z = fmaxf(b.z + dn * g.z, 0.0f);
        acc.w = fmaxf(b.w + dn * g.w, 0.0f);
    }
    if (OUTH) sth4(outh + (size_t)node * R2 + lane2, acc);
    else      outf[((size_t)node << LOG2C4) + lane] = acc;
}

// ---------------- layer-2 GEMM: z1 = A@WA (fp32), z2h = fp16(dinv.*(A@WB)) ----------------
template<int K, int JW>
__global__ __launch_bounds__(256) void gemm_k(const float* __restrict__ A,
                                              const float* __restrict__ WA,
                                              const float* __restrict__ WB,
                                              float* __restrict__ outA,
                                              __half2* __restrict__ outBh, int n,
                                              const float* __restrict__ dinv) {
    __shared__ float As[64 * 68];
    __shared__ float Ws[64 * 68];
    const int t = threadIdx.x;
    const int tj = t & 15;
    const int tn = t >> 4;
    const int n0 = blockIdx.x * 64;
    float acc[4][4] = {};

    for (int kc = 0; kc < K; kc += 64) {
        if (kc) __syncthreads();
        {
            int idx = t;
#pragma unroll
            for (int r = 0; r < 4; r++, idx += 256) {
                int nl = idx >> 4, q = idx & 15;
                int node = n0 + nl; node = node < n ? node : n - 1;
                float4 a = ((const float4*)A)[(size_t)node * (K / 4) + (kc >> 2) + q];
                *(float4*)&As[nl * 68 + q * 4] = a;
            }
        }
        {
            int idx = t;
#pragma unroll
            for (int r = 0; r < 4; r++, idx += 256) {
                int kl = idx >> 4, j4 = idx & 15;
                const float* W = (j4 < 8) ? WA : WB;
                float4 w = ((const float4*)W)[(size_t)(kc + kl) * 8 + (j4 & 7)];
                *(float4*)&Ws[kl * 68 + j4 * 4] = w;
            }
        }
        __syncthreads();

        const float* ap = &As[tn * 4 * 68];
        const float* wp = &Ws[tj * 4];
#pragma unroll 4
        for (int k4 = 0; k4 < 16; k4++) {
            float4 a0 = *(const float4*)&ap[0 * 68 + k4 * 4];
            float4 a1 = *(const float4*)&ap[1 * 68 + k4 * 4];
            float4 a2 = *(const float4*)&ap[2 * 68 + k4 * 4];
            float4 a3 = *(const float4*)&ap[3 * 68 + k4 * 4];
            float4 w0 = *(const float4*)&wp[(k4 * 4 + 0) * 68];
            float4 w1 = *(const float4*)&wp[(k4 * 4 + 1) * 68];
            float4 w2 = *(const float4*)&wp[(k4 * 4 + 2) * 68];
            float4 w3 = *(const float4*)&wp[(k4 * 4 + 3) * 68];
#define FMA_ROW(m, AV)                                                   \
            acc[m][0] += AV.x * w0.x + AV.y * w1.x + AV.z * w2.x + AV.w * w3.x; \
            acc[m][1] += AV.x * w0.y + AV.y * w1.y + AV.z * w2.y + AV.w * w3.y; \
            acc[m][2] += AV.x * w0.z + AV.y * w1.z + AV.z * w2.z + AV.w * w3.z; \
            acc[m][3] += AV.x * w0.w + AV.y * w1.w + AV.z * w2.w + AV.w * w3.w;
            FMA_ROW(0, a0)
            FMA_ROW(1, a1)
            FMA_ROW(2, a2)
            FMA_ROW(3, a3)
#undef FMA_ROW
        }
    }

    int mat = tj >> 3;
    int jw = tj & 7;
#pragma unroll
    for (int m = 0; m < 4; m++) {
        int node = n0 + tn * 4 + m;
        if (node < n) {
            if (mat) {
                float sc = dinv[node];
                sth4(outBh + (size_t)node * 16 + jw * 2,
                     make_float4(sc * acc[m][0], sc * acc[m][1],
                                 sc * acc[m][2], sc * acc[m][3]));
            } else {
                *(float4*)&outA[(size_t)node * JW + jw * 4] =
                    make_float4(acc[m][0], acc[m][1], acc[m][2], acc[m][3]);
            }
        }
    }
}

// ---------------- fused: final prop (C=32, fp16 gather) + heads ----------------
__global__ __launch_bounds__(256) void prop_heads_k(const __half2* __restrict__ hsrc,
                                                    const float* __restrict__ b2,
                                                    const int* __restrict__ rowsS,
                                                    const int* __restrict__ col,
                                                    const float* __restrict__ dinv,
                                                    const float* __restrict__ Wp1, const float* __restrict__ bp1,
                                                    const float* __restrict__ Wp2, const float* __restrict__ bp2,
                                                    const float* __restrict__ Wc1, const float* __restrict__ bc1,
                                                    const float* __restrict__ Wc2, const float* __restrict__ bc2,
                                                    float* __restrict__ coord, float* __restrict__ z) {
    __shared__ float sWp1[32 * 32], sWp2[32 * 32], sWc1[32 * 16], sWc2[32];
    __shared__ float sbp1[32], sbp2[32], sbc1[16], sbc2[2];
    __shared__ float sh[32 * 36], st[32 * 36], stc[32 * 18];
    const int t = threadIdx.x;
    for (int i = t; i < 1024; i += 256) { sWp1[i] = Wp1[i]; sWp2[i] = Wp2[i]; }
    for (int i = t; i < 512; i += 256) sWc1[i] = Wc1[i];
    if (t < 32) { sWc2[t] = Wc2[t]; sbp1[t] = bp1[t]; sbp2[t] = bp2[t]; }
    if (t < 16) sbc1[t] = bc1[t];
    if (t < 2) sbc2[t] = bc2[t];

    const int n0 = blockIdx.x * 32;
    const int nl = t >> 3;
    const int jq = t & 7;
    const int node = n0 + nl;

    // ---- propagation for this node's 4-float fragment ----
    float4 acc = make_float4(0.f, 0.f, 0.f, 0.f);
    if (node < NN) {
        size_t lane2 = (size_t)jq * 2;
        float dn = dinv[node];
        float4 g = ldh4(hsrc + (size_t)node * 16 + lane2);   // self term
        int rs = rowsS[node << 2];
        int re = rowsS[(node << 2) + 4];
        int4 c = *(const int4*)(col + rs);
        for (int i = rs; i < re; i += 4) {
            int4 cc = c;
            c = *(const int4*)(col + i + 4);
            float4 v0 = ldh4(hsrc + (size_t)cc.x * 16 + lane2);
            float4 v1 = ldh4(hsrc + (size_t)cc.y * 16 + lane2);
            float4 v2 = ldh4(hsrc + (size_t)cc.z * 16 + lane2);
            float4 v3 = ldh4(hsrc + (size_t)cc.w * 16 + lane2);
            g.x += v0.x + v1.x + v2.x + v3.x;
            g.y += v0.y + v1.y + v2.y + v3.y;
            g.z += v0.z + v1.z + v2.z + v3.z;
            g.w += v0.w + v1.w + v2.w + v3.w;
        }
        float4 b = ((const float4*)b2)[jq];
        acc.x = fmaxf(b.x + dn * g.x, 0.0f);
        acc.y = fmaxf(b.y + dn * g.y, 0.0f);
        acc.z = fmaxf(b.z + dn * g.z, 0.0f);
        acc.w = fmaxf(b.w + dn * g.w, 0.0f);
    }
    *(float4*)&sh[nl * 36 + jq * 4] = acc;
    __syncthreads();

    // ---- heads ----
    float4 a = *(const float4*)&sbp1[jq * 4];
#pragma unroll
    for (int k = 0; k < 32; k++) {
        float hv = sh[nl * 36 + k];
        float4 w = *(const float4*)&sWp1[k * 32 + jq * 4];
        a.x += hv * w.x; a.y += hv * w.y; a.z += hv * w.z; a.w += hv * w.w;
    }
    a.x = fmaxf(a.x, 0.f); a.y = fmaxf(a.y, 0.f);
    a.z = fmaxf(a.z, 0.f); a.w = fmaxf(a.w, 0.f);
    *(float4*)&st[nl * 36 + jq * 4] = a;

    float2 cc2 = *(const float2*)&sbc1[jq * 2];
#pragma unroll
    for (int k = 0; k < 32; k++) {
        float hv = sh[nl * 36 + k];
        float2 w = *(const float2*)&sWc1[k * 16 + jq * 2];
        cc2.x += hv * w.x; cc2.y += hv * w.y;
    }
    cc2.x = fmaxf(cc2.x, 0.f); cc2.y = fmaxf(cc2.y, 0.f);
    *(float2*)&stc[nl * 18 + jq * 2] = cc2;
    __syncthreads();

    float4 zz = *(const float4*)&sbp2[jq * 4];
#pragma unroll
    for (int k = 0; k < 32; k++) {
        float tv = st[nl * 36 + k];
        float4 w = *(const float4*)&sWp2[k * 32 + jq * 4];
        zz.x += tv * w.x; zz.y += tv * w.y; zz.z += tv * w.z; zz.w += tv * w.w;
    }
    if (node < NN) *(float4*)&z[(size_t)node * 32 + jq * 4] = zz;

    if (jq < 2) {
        float s = sbc2[jq];
#pragma unroll
        for (int k = 0; k < 16; k++) s += stc[nl * 18 + k] * sWc2[k * 2 + jq];
        if (node < NN) coord[(size_t)node * 2 + jq] = s;
    }
}

extern "C" void kernel_launch(void* const* d_in, const int* in_sizes, int n_in,
                              void* d_out, int out_size, void* d_ws, size_t ws_size,
                              hipStream_t stream) {
    const float* x    = (const float*)d_in[0];
    const int*   ei   = (const int*)d_in[1];
    const int*   src  = ei;
    const int*   dst  = ei + NE;
    const float* W1_1 = (const float*)d_in[2];
    const float* W1_2 = (const float*)d_in[3];
    const float* b1   = (const float*)d_in[4];
    const float* W2_1 = (const float*)d_in[5];
    const float* W2_2 = (const float*)d_in[6];
    const float* b2   = (const float*)d_in[7];
    const float* Wp1  = (const float*)d_in[8];
    const float* bp1  = (const float*)d_in[9];
    const float* Wp2  = (const float*)d_in[10];
    const float* bp2  = (const float*)d_in[11];
    const float* Wc1  = (const float*)d_in[12];
    const float* bc1  = (const float*)d_in[13];
    const float* Wc2  = (const float*)d_in[14];
    const float* bc2  = (const float*)d_in[15];

    // workspace layout (words), every base %4==0 -> 16B alignment:
    // dinv 50004 | cnt 200000 | rowsS 200004 | bsum 1024 | rank 800000 |
    // col COLCAP(1400008) | y1 NN*64 | z1 NN*32 | y2h | uh | z2h | u2h  (~49 MB)
    float*   ws    = (float*)d_ws;
    float*   dinv  = ws;                                // NN (padded to 50004)
    int*     cnt   = (int*)(ws + 50004);                // NN4
    int*     rowsS = cnt + NN4;                         // NN4+4
    int*     bsum  = rowsS + NN4 + 4;                   // 1024
    int*     rank  = bsum + 1024;                       // NE
    int*     col   = rank + NE;                         // COLCAP
    float*   y1    = (float*)(col + COLCAP);            // NN*64 fp32 (addin; reused as h1)
    float*   z1    = y1 + (size_t)NN * 64;              // NN*32 fp32 (addin)
    __half2* y2h   = (__half2*)(z1 + (size_t)NN * 32);  // (NN+1)*32 h2 = 64 halfs/row
    __half2* uh    = y2h + (size_t)(NN + 1) * 32;       // (NN+1)*32 h2
    __half2* z2h   = uh + (size_t)(NN + 1) * 32;        // (NN+1)*16 h2 = 32 halfs/row
    __half2* u2h   = z2h + (size_t)(NN + 1) * 16;       // (NN+1)*16 h2
    float*   h1    = y1;                                // y1 dead after prop5

    float* coord = (float*)d_out;                   // NN*2
    float* z     = (float*)d_out + 2 * NN;          // NN*32

    // 1) zero bucket counters (memset node, no kernel launch)
    hipMemsetAsync(cnt, 0, NN4 * sizeof(int), stream);
    // 2) hist: 4 edges/thread
    hist_k<<<NBH4, 256, 0, stream>>>(src, dst, cnt, rank);
    // 3) scan chain (padded buckets) + dinv + fp16 sentinel-row zeroing
    sum_blocks_k<<<NBLK2, 256, 0, stream>>>(cnt, bsum, dinv,
                                            (unsigned*)(y2h + (size_t)NN * 32),
                                            (unsigned*)(uh + (size_t)NN * 32),
                                            (unsigned*)(z2h + (size_t)NN * 16),
                                            (unsigned*)(u2h + (size_t)NN * 16));
    scan_final_k<<<NBLK2, 256, 0, stream>>>(cnt, bsum, rowsS);
    // 4) gemm1 (y1 = xW1 fp32, y2h = fp16(dinv.*xW2)) || scatter+padfill
    gemm1_scatter_k<<<NBG + NBH4, 256, 0, stream>>>(x, W1_1, W1_2, y1, y2h,
                                                    src, dst, rank, rowsS, cnt, col, dinv);

    // 5) uh = fp16(dinv.*(y1 + dn*(self+sum y2h)))   (C=64)
    prop_k<4, true, true><<<(NN * 16 + 255) / 256, 256, 0, stream>>>(
        y2h, (const float4*)y1, nullptr, nullptr, uh, rowsS, col, dinv);
    // 6) h1 = relu(b1 + dn*(self+sum uh))            (C=64, fp32 for gemm2)
    prop_k<4, false, false><<<(NN * 16 + 255) / 256, 256, 0, stream>>>(
        uh, nullptr, b1, (float4*)h1, nullptr, rowsS, col, dinv);
    // 7) z1 = h1@W2_1 (fp32), z2h = fp16(dinv.*(h1@W2_2))  (K=64)
    gemm_k<64, 32><<<(NN + 63) / 64, 256, 0, stream>>>(h1, W2_1, W2_2, z1, z2h, NN, dinv);
    // 8) u2h = fp16(dinv.*(z1 + dn*(self+sum z2h)))  (C=32)
    prop_k<3, true, true><<<(NN * 8 + 255) / 256, 256, 0, stream>>>(
        z2h, (const float4*)z1, nullptr, nullptr, u2h, rowsS, col, dinv);
    // 9) h2 = relu(b2 + dn*(self+sum u2h)) fused with heads (h2 never hits HBM)
    prop_heads_k<<<(NN + 31) / 32, 256, 0, stream>>>(
        u2h, b2, rowsS, col, dinv,
        Wp1, bp1, Wp2, bp2, Wc1, bc1, Wc2, bc2, coord, z);
}